// Round 18
// baseline (145.497 us; speedup 1.0000x reference)
//
#include <hip/hip_runtime.h>
#include <hip/hip_bf16.h>

#define TEMP_INV (1.0f / 0.07f)
#define LOG2E 1.4426950408889634f
#define LN2 0.6931471805599453f
#define CFIX 21.0f

typedef __attribute__((ext_vector_type(4))) float f32x4;

// ---------------- Kernel 1: L2-normalize -> fp8(e4m3) x16 in FRAGMENT layout,
// ---------------- cross dot, zero lsum (folded). ----------------------------
// Fr layout: [kb 0..31][rb 0..NN/16-1][512B frag]; frag byte (hi*16+lo)*8+o =
// fp8(F[rb*16+lo][kb*32+hi*8+o]).  One 512B frag = one MFMA operand for a
// whole wave, loaded as lane-contiguous dwordx2 (perfect coalescing).
__global__ __launch_bounds__(256) void norm_kernel(
    const float* __restrict__ A, const float* __restrict__ P,
    unsigned char* __restrict__ Fr, float* __restrict__ cross,
    float* __restrict__ lsum, int B, int D) {
  const int row = blockIdx.x;
  const int t = threadIdx.x;
  {
    const int zi = row * 256 + t;
    if (zi < 2 * B) lsum[zi] = 0.f;
  }
  const float4* a4 = reinterpret_cast<const float4*>(A + (size_t)row * D);
  const float4* p4 = reinterpret_cast<const float4*>(P + (size_t)row * D);
  const int n4 = D >> 2;  // 256
  float sa = 0.f, sp = 0.f, sx = 0.f;
  for (int i = t; i < n4; i += 256) {
    float4 av = a4[i], pv = p4[i];
    sa += av.x * av.x + av.y * av.y + av.z * av.z + av.w * av.w;
    sp += pv.x * pv.x + pv.y * pv.y + pv.z * pv.z + pv.w * pv.w;
    sx += av.x * pv.x + av.y * pv.y + av.z * pv.z + av.w * pv.w;
  }
#pragma unroll
  for (int off = 32; off; off >>= 1) {
    sa += __shfl_down(sa, off);
    sp += __shfl_down(sp, off);
    sx += __shfl_down(sx, off);
  }
  __shared__ float red[3][4];
  const int wid = t >> 6, lane = t & 63;
  if (lane == 0) { red[0][wid] = sa; red[1][wid] = sp; red[2][wid] = sx; }
  __syncthreads();
  sa = red[0][0] + red[0][1] + red[0][2] + red[0][3];
  sp = red[1][0] + red[1][1] + red[1][2] + red[1][3];
  sx = red[2][0] + red[2][1] + red[2][2] + red[2][3];
  const float ian = rsqrtf(sa), ipn = rsqrtf(sp);
  const float ia = ian * 16.f, ip = ipn * 16.f;  // x16 -> e4m3 range
  const int NN16 = (2 * B) >> 4;                 // rbs per kb block
  const size_t KBSTR = (size_t)NN16 * 512;       // bytes per kb block
  // this thread: k-quad i=t -> kb=i>>3, hi=(i>>1)&3, half=(i&1)*4
  const int kb = t >> 3, hi = (t >> 1) & 3, half = (t & 1) * 4;
  const int rbA = row >> 4, rbP = (B + row) >> 4;
  const int lo = row & 15;
  const size_t off8 = (size_t)kb * KBSTR + ((hi << 4) + lo) * 8 + half;
  for (int i = t; i < n4; i += 256) {
    float4 av = a4[i], pv = p4[i];
    int qa = 0, qp = 0;
    qa = __builtin_amdgcn_cvt_pk_fp8_f32(av.x * ia, av.y * ia, qa, false);
    qa = __builtin_amdgcn_cvt_pk_fp8_f32(av.z * ia, av.w * ia, qa, true);
    qp = __builtin_amdgcn_cvt_pk_fp8_f32(pv.x * ip, pv.y * ip, qp, false);
    qp = __builtin_amdgcn_cvt_pk_fp8_f32(pv.z * ip, pv.w * ip, qp, true);
    *reinterpret_cast<int*>(Fr + off8 + (size_t)rbA * 512) = qa;
    *reinterpret_cast<int*>(Fr + off8 + (size_t)rbP * 512) = qp;
  }
  if (t == 0) cross[row] = sx * ian * ipn;
}

// ---------------- Kernel 2: triangular fused Gram — NO LDS, reg-direct -------
// 128x128 triangle tiles (2080 = 8*260), FULL K=1024. 256 threads / 4 waves
// (wr=w>>1 j-64, wn=w&1 i-64). Every MFMA operand is one coalesced 512B
// global load (dwordx2/lane) from Fr -> registers. No LDS, no barriers, no
// staging: waves desync freely so L2 latency hides under sibling waves' MFMAs
// (the six barrier-locked LDS schedules R12-R17 all pinned at 25-31% Mfma).
// Reg ping/pong double-buffer one K-32 step ahead; compiler inserts counted
// vmcnt (R14 lesson: its scheduling beats hand-placed waits here).
// acc[4][4]=64 + frags 32 + addr ~12 => ~110 VGPR -> 4 blocks/CU (16 waves).
__global__ __launch_bounds__(256, 4) void gram_kernel(
    const unsigned char* __restrict__ Fr, float* __restrict__ lsum, int NN,
    int D) {
  const int nrb = NN >> 7;               // 64 row-panels of 128
  const int ntri = nrb * (nrb + 1) / 2;  // 2080
  int lin = blockIdx.x;
  lin = (lin & 7) * (ntri >> 3) + (lin >> 3);  // XCD swizzle (2080 = 8*260)
  int by = (int)((sqrtf(8.f * (float)lin + 1.f) - 1.f) * 0.5f);
  while ((by + 1) * (by + 2) / 2 <= lin) ++by;
  while (by * (by + 1) / 2 > lin) --by;
  const int bx = lin - by * (by + 1) / 2;  // bx <= by
  const int r0 = bx * 128;  // i rows (B operand, N side)
  const int c0 = by * 128;  // j rows (A operand, M side)
  const bool diag = (bx == by);

  const int t = threadIdx.x;
  const int lane = t & 63, w = t >> 6;  // 4 waves
  const int lo = lane & 15, hi = lane >> 4;
  const int wr = w >> 1, wn = w & 1;  // wr: j-64 half, wn: i-64 half

  const size_t KBSTR = (size_t)(NN >> 4) * 512;  // bytes per kb block
  // frag base (kb=0): A rb = c0/16 + wr*4 + mf ; B rb = r0/16 + wn*4 + nf.
  // mf/nf step = 512 B (fits immediate offsets).
  const unsigned char* pA =
      Fr + (size_t)((c0 >> 4) + wr * 4) * 512 + (size_t)lane * 8;
  const unsigned char* pB =
      Fr + (size_t)((r0 >> 4) + wn * 4) * 512 + (size_t)lane * 8;

  f32x4 acc[4][4];
#pragma unroll
  for (int a = 0; a < 4; ++a)
#pragma unroll
    for (int bb = 0; bb < 4; ++bb) acc[a][bb] = (f32x4){0.f, 0.f, 0.f, 0.f};

  long aP[4], bP[4], aQ[4], bQ[4];
#pragma unroll
  for (int q = 0; q < 4; ++q) {  // kb = 0
    aP[q] = *(const long*)(pA + q * 512);
    bP[q] = *(const long*)(pB + q * 512);
  }

  for (int kb = 0; kb < 32; kb += 2) {
    // prefetch kb+1 into Q
#pragma unroll
    for (int q = 0; q < 4; ++q) {
      aQ[q] = *(const long*)(pA + KBSTR + q * 512);
      bQ[q] = *(const long*)(pB + KBSTR + q * 512);
    }
    __builtin_amdgcn_s_setprio(1);
#pragma unroll
    for (int mf = 0; mf < 4; ++mf)
#pragma unroll
      for (int nf = 0; nf < 4; ++nf)
        acc[mf][nf] = __builtin_amdgcn_mfma_f32_16x16x32_fp8_fp8(
            aP[mf], bP[nf], acc[mf][nf], 0, 0, 0);
    __builtin_amdgcn_s_setprio(0);
    pA += 2 * KBSTR;
    pB += 2 * KBSTR;
    if (kb + 2 < 32) {  // prefetch kb+2 into P
#pragma unroll
      for (int q = 0; q < 4; ++q) {
        aP[q] = *(const long*)(pA + q * 512);
        bP[q] = *(const long*)(pB + q * 512);
      }
    }
    __builtin_amdgcn_s_setprio(1);
#pragma unroll
    for (int mf = 0; mf < 4; ++mf)
#pragma unroll
      for (int nf = 0; nf < 4; ++nf)
        acc[mf][nf] = __builtin_amdgcn_mfma_f32_16x16x32_fp8_fp8(
            aQ[mf], bQ[nf], acc[mf][nf], 0, 0, 0);
    __builtin_amdgcn_s_setprio(0);
  }

  // ---- dual-side epilogue (R16/R17-proven 64x64 wave-tile mapping) ----
  // acc[mf][nf][rg]: j = c0 + wr*64 + mf*16 + hi*4 + rg
  //                  i = r0 + wn*64 + nf*16 + lo
  const float scl = LOG2E * TEMP_INV / 256.f;  // descale x16*x16
  float s_i[4] = {0.f, 0.f, 0.f, 0.f};
  float s_j[16];
#pragma unroll
  for (int q = 0; q < 16; ++q) s_j[q] = 0.f;
  {
    const int dgb = (r0 + wn * 64) - (c0 + wr * 64);
#pragma unroll
    for (int nf = 0; nf < 4; ++nf) {
      const int dg = dgb + nf * 16 + lo;
#pragma unroll
      for (int mf = 0; mf < 4; ++mf)
#pragma unroll
        for (int rg = 0; rg < 4; ++rg) {
          const int jloc = mf * 16 + hi * 4 + rg;
          float e = exp2f(acc[mf][nf][rg] * scl - CFIX);
          if (diag && dg == jloc) e = 0.f;
          s_i[nf] += e;
          s_j[mf * 4 + rg] += e;
        }
    }
  }
#pragma unroll
  for (int nf = 0; nf < 4; ++nf) {
    float v = s_i[nf];
    v += __shfl_xor(v, 16);
    v += __shfl_xor(v, 32);
    if (hi == 0) atomicAdd(&lsum[r0 + wn * 64 + nf * 16 + lo], v);
  }
  if (!diag) {
#pragma unroll
    for (int q = 0; q < 16; ++q) {
      float v = s_j[q];
      v += __shfl_xor(v, 1);
      v += __shfl_xor(v, 2);
      v += __shfl_xor(v, 4);
      v += __shfl_xor(v, 8);
      if (lo == 0)
        atomicAdd(&lsum[c0 + wr * 64 + (q >> 2) * 16 + hi * 4 + (q & 3)], v);
    }
  }
}

// ---------------- Kernel 3a: per-row loss -> per-block partial sums ----------
__global__ __launch_bounds__(256) void finalize_part(
    const float* __restrict__ lsum, const float* __restrict__ cross,
    const int* __restrict__ labels, float* __restrict__ bsum,
    float* __restrict__ bcnt, int B) {
  const int NN = 2 * B;
  const int i = blockIdx.x * 256 + threadIdx.x;
  float sum = 0.f, cnt = 0.f;
  if (i < NN) {
    const float lse = LN2 * (CFIX + log2f(lsum[i]));
    const float lab = (float)labels[i % B];
    sum = (lse - cross[i % B] * TEMP_INV) * lab;
    cnt = lab;
  }
#pragma unroll
  for (int off = 32; off; off >>= 1) {
    sum += __shfl_down(sum, off);
    cnt += __shfl_down(cnt, off);
  }
  __shared__ float rs[4], rc[4];
  const int wid = threadIdx.x >> 6, lane = threadIdx.x & 63;
  if (lane == 0) { rs[wid] = sum; rc[wid] = cnt; }
  __syncthreads();
  if (threadIdx.x == 0) {
    bsum[blockIdx.x] = rs[0] + rs[1] + rs[2] + rs[3];
    bcnt[blockIdx.x] = rc[0] + rc[1] + rc[2] + rc[3];
  }
}

// ---------------- Kernel 3b: final reduce ------------------------------------
__global__ __launch_bounds__(64) void finalize_final(
    const float* __restrict__ bsum, const float* __restrict__ bcnt,
    float* __restrict__ out, int nb) {
  const int t = threadIdx.x;
  float s = (t < nb) ? bsum[t] : 0.f;
  float c = (t < nb) ? bcnt[t] : 0.f;
#pragma unroll
  for (int off = 32; off; off >>= 1) {
    s += __shfl_down(s, off);
    c += __shfl_down(c, off);
  }
  if (t == 0) out[0] = (c > 0.f) ? s / c : 0.f;
}

extern "C" void kernel_launch(void* const* d_in, const int* in_sizes, int n_in,
                              void* d_out, int out_size, void* d_ws, size_t ws_size,
                              hipStream_t stream) {
  const float* A = (const float*)d_in[0];
  const float* P = (const float*)d_in[1];
  const int* labels = (const int*)d_in[2];
  float* out = (float*)d_out;
  const int B = in_sizes[2];
  const int D = in_sizes[0] / B;
  const int NN = 2 * B;

  char* ws = (char*)d_ws;
  unsigned char* Fr = (unsigned char*)ws;
  size_t off = (size_t)NN * D;  // fp8 fragment-layout copy
  off = (off + 255) & ~(size_t)255;
  float* cross = (float*)(ws + off);
  off += (size_t)B * sizeof(float);
  off = (off + 255) & ~(size_t)255;
  float* lsum = (float*)(ws + off);
  off += (size_t)NN * sizeof(float);
  off = (off + 255) & ~(size_t)255;
  float* bsum = (float*)(ws + off);
  off += 64 * sizeof(float);
  float* bcnt = (float*)(ws + off);

  norm_kernel<<<B, 256, 0, stream>>>(A, P, Fr, cross, lsum, B, D);
  const int nrb = NN >> 7;               // 64 row-panels of 128
  const int ntri = nrb * (nrb + 1) / 2;  // 2080 triangle tiles
  gram_kernel<<<ntri, 256, 0, stream>>>(Fr, lsum, NN, D);
  const int nb = (NN + 255) / 256;  // 32
  finalize_part<<<nb, 256, 0, stream>>>(lsum, cross, labels, bsum, bcnt, B);
  finalize_final<<<1, 64, 0, stream>>>(bsum, bcnt, out, nb);
}

// Round 19
// 115.352 us; speedup vs baseline: 1.2613x; 1.2613x over previous
//
#include <hip/hip_runtime.h>
#include <hip/hip_bf16.h>

#define TEMP_INV (1.0f / 0.07f)
#define LOG2E 1.4426950408889634f
#define LN2 0.6931471805599453f
#define CFIX 21.0f

typedef __attribute__((ext_vector_type(4))) float f32x4;

__device__ __forceinline__ void gload16(const unsigned char* g,
                                        unsigned char* l) {
  __builtin_amdgcn_global_load_lds(
      (const __attribute__((address_space(1))) void*)g,
      (__attribute__((address_space(3))) void*)l, 16, 0, 0);
}

// ---------------- Kernel 1: L2-normalize -> fp8(e4m3) feats x16, cross, ------
// ---------------- and zero lsum (folded) -------------------------------------
__global__ __launch_bounds__(256) void norm_kernel(
    const float* __restrict__ A, const float* __restrict__ P,
    unsigned char* __restrict__ F, float* __restrict__ cross,
    float* __restrict__ lsum, int B, int D) {
  const int row = blockIdx.x;
  const int t = threadIdx.x;
  {
    const int zi = row * 256 + t;
    if (zi < 2 * B) lsum[zi] = 0.f;
  }
  const float4* a4 = reinterpret_cast<const float4*>(A + (size_t)row * D);
  const float4* p4 = reinterpret_cast<const float4*>(P + (size_t)row * D);
  const int n4 = D >> 2;
  float sa = 0.f, sp = 0.f, sx = 0.f;
  for (int i = t; i < n4; i += 256) {
    float4 av = a4[i], pv = p4[i];
    sa += av.x * av.x + av.y * av.y + av.z * av.z + av.w * av.w;
    sp += pv.x * pv.x + pv.y * pv.y + pv.z * pv.z + pv.w * pv.w;
    sx += av.x * pv.x + av.y * pv.y + av.z * pv.z + av.w * pv.w;
  }
#pragma unroll
  for (int off = 32; off; off >>= 1) {
    sa += __shfl_down(sa, off);
    sp += __shfl_down(sp, off);
    sx += __shfl_down(sx, off);
  }
  __shared__ float red[3][4];
  const int wid = t >> 6, lane = t & 63;
  if (lane == 0) { red[0][wid] = sa; red[1][wid] = sp; red[2][wid] = sx; }
  __syncthreads();
  sa = red[0][0] + red[0][1] + red[0][2] + red[0][3];
  sp = red[1][0] + red[1][1] + red[1][2] + red[1][3];
  sx = red[2][0] + red[2][1] + red[2][2] + red[2][3];
  const float ian = rsqrtf(sa), ipn = rsqrtf(sp);
  const float ia = ian * 16.f, ip = ipn * 16.f;  // x16 -> e4m3 range
  unsigned char* fa = F + (size_t)row * D;
  unsigned char* fp = F + (size_t)(B + row) * D;
  for (int i = t; i < n4; i += 256) {
    float4 av = a4[i], pv = p4[i];
    int qa = 0, qp = 0;
    qa = __builtin_amdgcn_cvt_pk_fp8_f32(av.x * ia, av.y * ia, qa, false);
    qa = __builtin_amdgcn_cvt_pk_fp8_f32(av.z * ia, av.w * ia, qa, true);
    qp = __builtin_amdgcn_cvt_pk_fp8_f32(pv.x * ip, pv.y * ip, qp, false);
    qp = __builtin_amdgcn_cvt_pk_fp8_f32(pv.z * ip, pv.w * ip, qp, true);
    reinterpret_cast<int*>(fa)[i] = qa;
    reinterpret_cast<int*>(fp)[i] = qp;
  }
  if (t == 0) cross[row] = sx * ian * ipn;
}

// ---------------- Kernel 2: triangular fused Gram (fp8, 4-deep pipeline) -----
// R12 configuration (measured best total: 115.4 us; gram 108 us, FETCH 39 MB,
// zero spill). 256x256 triangle tiles, FULL K=1024, 8 waves (2x4),
// 16x16x32 fp8 MFMA. 176 blocks x exactly 3 tiles (528 = 176*3).
// LDS = 4 tile-buffers x (A,B) x (k0,k1) x 8KB = 128KB -> tiles t+1..t+3 in
// flight => HBM/L2 latency hidden (Little's-law lesson from R10/R11).
// Schedule per K-64 iter t: {vmcnt(8); barrier; [KS0: read frags, stage
// A/B(t+3,k0), 32 MFMA]; [KS1: same with k1]}. Buffer (t+3)&3 WAR-safe:
// last read at iter t-1, consumed before this iter's barrier. Tail: clamped
// dummy stages keep vmcnt counts uniform (R8/R11 class of bug).
// Inter-tile: vmcnt(0)+barrier.
// fp8 region (256 trows x 32 k = 8KB): lrow=trow>>2 (128B bank period);
// cu=(trow&3)*2+(k>=16); chunk=cu^(lrow&7); byte=lrow*128+chunk*16+(k&15).
// Staged linear (chunk c = thread id), source carries inverse swizzle.
#define VT 16  /* K-64 tiles: D/64 */

__global__ __launch_bounds__(512, 2) void gram_lse_kernel(
    const unsigned char* __restrict__ F, float* __restrict__ lsum, int NN,
    int D) {
  __shared__ unsigned char lds8[4][2][2][8192];  // [buf][A/B][khalf][8KB]
  const int nrb = NN >> 8;
  const int ntri = nrb * (nrb + 1) / 2;
  int b = blockIdx.x;
  b = (b & 7) * (gridDim.x >> 3) + (b >> 3);  // XCD swizzle (176 = 8*22)
  const int lin0 = b * 3;

  const int t = threadIdx.x;
  const int lane = t & 63, w = t >> 6;
  const int lo = lane & 15, hi = lane >> 4;
  const int wr = w >> 2, wn = w & 3;  // wr: j-half(128), wn: i-quarter(64)

  // staging decode: chunk c = tid; lrow=c>>3; cu=(c&7)^(lrow&7);
  // trow=lrow*4+(cu>>1); kc=(cu&1)*16
  const int ci = t;
  const int lrS = ci >> 3, cuS = (ci & 7) ^ (lrS & 7);
  const int trowS = lrS * 4 + (cuS >> 1), kcS = (cuS & 1) << 4;
  const int dstW = w * 1024;  // wave-uniform byte base in 8KB region

  // fragment read byte offsets (region-relative, tile-independent)
  // r row, k-half hi: lrow=r>>2; cu=((r&3)<<1)|(hi>>1);
  // byte = lrow*128 + ((cu^(lrow&7))<<4) + (hi&1)*8
  int offA[8], offB[4];
#pragma unroll
  for (int mf = 0; mf < 8; ++mf) {
    const int r = wr * 128 + mf * 16 + lo;
    const int lr = r >> 2;
    const int cu = ((r & 3) << 1) | (hi >> 1);
    offA[mf] = lr * 128 + ((cu ^ (lr & 7)) << 4) + ((hi & 1) << 3);
  }
#pragma unroll
  for (int nf = 0; nf < 4; ++nf) {
    const int r = wn * 64 + nf * 16 + lo;
    const int lr = r >> 2;
    const int cu = ((r & 3) << 1) | (hi >> 1);
    offB[nf] = lr * 128 + ((cu ^ (lr & 7)) << 4) + ((hi & 1) << 3);
  }

  const float scl = LOG2E * TEMP_INV / 256.f;  // descale x16*x16

  for (int ti = 0; ti < 3; ++ti) {
    const int lin = lin0 + ti;
    int by = (int)((sqrtf(8.f * (float)lin + 1.f) - 1.f) * 0.5f);
    while ((by + 1) * (by + 2) / 2 <= lin) ++by;
    while (by * (by + 1) / 2 > lin) --by;
    const int bx = lin - by * (by + 1) / 2;  // bx <= by
    const int r0 = bx * 256;  // i rows (B operand, N side)
    const int c0 = by * 256;  // j rows (A operand, M side)
    const bool diag = (bx == by);

    const unsigned char* srcA = F + (size_t)(c0 + trowS) * D + kcS;
    const unsigned char* srcB = F + (size_t)(r0 + trowS) * D + kcS;

    // STAGE one 8KB region (1 gload16/thread). Clamp addr, UNclamped buf.
#define STAGE_A(T, KS)                                              \
  do {                                                              \
    int v_ = (T); if (v_ > VT - 1) v_ = VT - 1;                     \
    gload16(srcA + v_ * 64 + (KS) * 32, &lds8[(T) & 3][0][KS][dstW]); \
  } while (0)
#define STAGE_B(T, KS)                                              \
  do {                                                              \
    int v_ = (T); if (v_ > VT - 1) v_ = VT - 1;                     \
    gload16(srcB + v_ * 64 + (KS) * 32, &lds8[(T) & 3][1][KS][dstW]); \
  } while (0)

    f32x4 acc[8][4];
#pragma unroll
    for (int a = 0; a < 8; ++a)
#pragma unroll
      for (int bb = 0; bb < 4; ++bb) acc[a][bb] = (f32x4){0.f, 0.f, 0.f, 0.f};

    // prologue: tiles 0,1,2 fully staged (12 loads in flight)
#pragma unroll
    for (int pt = 0; pt < 3; ++pt) {
      STAGE_A(pt, 0); STAGE_B(pt, 0);
      STAGE_A(pt, 1); STAGE_B(pt, 1);
    }

    for (int v = 0; v < VT; ++v) {
      const int buf = v & 3;
      // tiles t+1, t+2 stay in flight (8 loads); tile t drained
      asm volatile("s_waitcnt vmcnt(8)" ::: "memory");
      __builtin_amdgcn_s_barrier();
      asm volatile("" ::: "memory");

#pragma unroll
      for (int KS = 0; KS < 2; ++KS) {
        const unsigned char* RA = &lds8[buf][0][KS][0];
        const unsigned char* RB = &lds8[buf][1][KS][0];
        long aF[8], bF[4];
#pragma unroll
        for (int nf = 0; nf < 4; ++nf) bF[nf] = *(const long*)(RB + offB[nf]);
#pragma unroll
        for (int mf = 0; mf < 8; ++mf) aF[mf] = *(const long*)(RA + offA[mf]);

        if (KS == 0) { STAGE_A(v + 3, 0); STAGE_B(v + 3, 0); }
        else         { STAGE_A(v + 3, 1); STAGE_B(v + 3, 1); }

        __builtin_amdgcn_s_setprio(1);
#pragma unroll
        for (int mf = 0; mf < 8; ++mf)
#pragma unroll
          for (int nf = 0; nf < 4; ++nf)
            acc[mf][nf] = __builtin_amdgcn_mfma_f32_16x16x32_fp8_fp8(
                aF[mf], bF[nf], acc[mf][nf], 0, 0, 0);
        __builtin_amdgcn_s_setprio(0);
      }
      asm volatile("" ::: "memory");
    }

    // ---- dual-side epilogue (verbatim mapping, absmax-0 verified R6-R17) ----
    // acc[mf][nf][rg]: j = c0 + wr*128 + mf*16 + hi*4 + rg
    //                  i = r0 + wn*64 + nf*16 + lo
    float s_i[4] = {0.f, 0.f, 0.f, 0.f};
    float s_j[32];
#pragma unroll
    for (int q = 0; q < 32; ++q) s_j[q] = 0.f;
    {
      const int jb2 = c0 + wr * 128;
#pragma unroll
      for (int nf = 0; nf < 4; ++nf) {
        const int dg = (r0 + wn * 64 + nf * 16 + lo) - jb2;
#pragma unroll
        for (int mf = 0; mf < 8; ++mf)
#pragma unroll
          for (int rg = 0; rg < 4; ++rg) {
            const int jloc = mf * 16 + hi * 4 + rg;
            float e = exp2f(acc[mf][nf][rg] * scl - CFIX);
            if (diag && dg == jloc) e = 0.f;
            s_i[nf] += e;
            s_j[mf * 4 + rg] += e;
          }
      }
    }
#pragma unroll
    for (int nf = 0; nf < 4; ++nf) {
      float v = s_i[nf];
      v += __shfl_xor(v, 16);
      v += __shfl_xor(v, 32);
      if (hi == 0) atomicAdd(&lsum[r0 + wn * 64 + nf * 16 + lo], v);
    }
    if (!diag) {
#pragma unroll
      for (int q = 0; q < 32; ++q) {
        float v = s_j[q];
        v += __shfl_xor(v, 1);
        v += __shfl_xor(v, 2);
        v += __shfl_xor(v, 4);
        v += __shfl_xor(v, 8);
        if (lo == 0)
          atomicAdd(&lsum[c0 + wr * 128 + (q >> 2) * 16 + hi * 4 + (q & 3)],
                    v);
      }
    }

    // drain dummy/clamped stages before next tile's prologue overwrites
    asm volatile("s_waitcnt vmcnt(0)" ::: "memory");
    __builtin_amdgcn_s_barrier();
    asm volatile("" ::: "memory");
#undef STAGE_A
#undef STAGE_B
  }
}

// ---------------- Kernel 3a: per-row loss -> per-block partial sums ----------
__global__ __launch_bounds__(256) void finalize_part(
    const float* __restrict__ lsum, const float* __restrict__ cross,
    const int* __restrict__ labels, float* __restrict__ bsum,
    float* __restrict__ bcnt, int B) {
  const int NN = 2 * B;
  const int i = blockIdx.x * 256 + threadIdx.x;
  float sum = 0.f, cnt = 0.f;
  if (i < NN) {
    const float lse = LN2 * (CFIX + log2f(lsum[i]));
    const float lab = (float)labels[i % B];
    sum = (lse - cross[i % B] * TEMP_INV) * lab;
    cnt = lab;
  }
#pragma unroll
  for (int off = 32; off; off >>= 1) {
    sum += __shfl_down(sum, off);
    cnt += __shfl_down(cnt, off);
  }
  __shared__ float rs[4], rc[4];
  const int wid = threadIdx.x >> 6, lane = threadIdx.x & 63;
  if (lane == 0) { rs[wid] = sum; rc[wid] = cnt; }
  __syncthreads();
  if (threadIdx.x == 0) {
    bsum[blockIdx.x] = rs[0] + rs[1] + rs[2] + rs[3];
    bcnt[blockIdx.x] = rc[0] + rc[1] + rc[2] + rc[3];
  }
}

// ---------------- Kernel 3b: final reduce ------------------------------------
__global__ __launch_bounds__(64) void finalize_final(
    const float* __restrict__ bsum, const float* __restrict__ bcnt,
    float* __restrict__ out, int nb) {
  const int t = threadIdx.x;
  float s = (t < nb) ? bsum[t] : 0.f;
  float c = (t < nb) ? bcnt[t] : 0.f;
#pragma unroll
  for (int off = 32; off; off >>= 1) {
    s += __shfl_down(s, off);
    c += __shfl_down(c, off);
  }
  if (t == 0) out[0] = (c > 0.f) ? s / c : 0.f;
}

extern "C" void kernel_launch(void* const* d_in, const int* in_sizes, int n_in,
                              void* d_out, int out_size, void* d_ws, size_t ws_size,
                              hipStream_t stream) {
  const float* A = (const float*)d_in[0];
  const float* P = (const float*)d_in[1];
  const int* labels = (const int*)d_in[2];
  float* out = (float*)d_out;
  const int B = in_sizes[2];
  const int D = in_sizes[0] / B;
  const int NN = 2 * B;

  char* ws = (char*)d_ws;
  unsigned char* F = (unsigned char*)ws;
  size_t off = (size_t)NN * D;  // fp8: 1 B/elem
  off = (off + 255) & ~(size_t)255;
  float* cross = (float*)(ws + off);
  off += (size_t)B * sizeof(float);
  off = (off + 255) & ~(size_t)255;
  float* lsum = (float*)(ws + off);
  off += (size_t)NN * sizeof(float);
  off = (off + 255) & ~(size_t)255;
  float* bsum = (float*)(ws + off);
  off += 64 * sizeof(float);
  float* bcnt = (float*)(ws + off);

  norm_kernel<<<B, 256, 0, stream>>>(A, P, F, cross, lsum, B, D);
  const int nrb = NN >> 8;               // 32 row-panels of 256
  const int ntri = nrb * (nrb + 1) / 2;  // 528 = 176 * 3 exactly
  gram_lse_kernel<<<ntri / 3, 512, 0, stream>>>(F, lsum, NN, D);
  const int nb = (NN + 255) / 256;  // 32
  finalize_part<<<nb, 256, 0, stream>>>(lsum, cross, labels, bsum, bcnt, B);
  finalize_final<<<1, 64, 0, stream>>>(bsum, bcnt, out, nb);
}